// Round 2
// baseline (191.039 us; speedup 1.0000x reference)
//
#include <hip/hip_runtime.h>
#include <math.h>

// Problem constants (reference: B=16, C=2, H=512, W=512; gt in {0,1})
constexpr int BATCH = 16;
constexpr int H = 512;
constexpr int W = 512;
constexpr float INV_N = 1.0f / (float)(16 * 512 * 512);  // mean over B*H*W

// One block per (batch, row): 512 threads, one per column.
// Vertical EDT: batched speculative scan (4 up + 4 down independent loads
// per iteration) to break the dependent-load latency chain.
// Horizontal exact min-plus on the d1 row in LDS, 4 offsets per iteration
// (unconditional candidates are valid upper bounds; exact break t^2 >= best).
__global__ __launch_bounds__(512) void boundary_loss_kernel(
    const float* __restrict__ probs,  // [B, 2, H, W]
    const int* __restrict__ gt,       // [B, 1, H, W]
    float* __restrict__ out)          // [1]
{
    const int row = blockIdx.x;       // 0 .. B*H-1
    const int b = row >> 9;           // row / 512
    const int i = row & 511;          // row % 512
    const int j = threadIdx.x;        // 0 .. W-1

    const int* colp = gt + (size_t)b * (H * W) + j;

    // Issue the probs load early; consumed only in the epilogue.
    const float p = probs[(size_t)b * 2 * H * W + (size_t)i * W + j];

    // --- vertical nearest-foreground, batched both directions ---
    const int center = colp[i * W];
    int tu = center ? 0 : -1;   // distance to nearest fg at-or-above
    int td = center ? 0 : -1;   // distance to nearest fg at-or-below
    {
        int t = 1;
        const int up_max = i;          // max distance upward
        const int dn_max = H - 1 - i;  // max distance downward
        while (((tu < 0) & (t <= up_max)) | ((td < 0) & (t <= dn_max))) {
            int vu[4], vd[4];
            #pragma unroll
            for (int k = 0; k < 4; ++k) {
                const int ti = t + k;
                vu[k] = (tu < 0 && ti <= up_max) ? colp[(i - ti) * W] : 0;
                vd[k] = (td < 0 && ti <= dn_max) ? colp[(i + ti) * W] : 0;
            }
            #pragma unroll
            for (int k = 0; k < 4; ++k) {
                const int ti = t + k;
                if (tu < 0 && vu[k]) tu = ti;
                if (td < 0 && vd[k]) td = ti;
            }
            t += 4;
        }
    }
    // Reference sentinels (BIG = 2*(H+W) = 2048) for fg-free half-columns:
    const int du = (tu >= 0) ? tu * tu : (i + 2048) * (i + 2048);
    const int dd = (td >= 0) ? td * td : (2560 - i) * (2560 - i);
    const int d1 = min(du, dd);

    __shared__ int d1row[W];
    d1row[j] = d1;
    __syncthreads();

    // --- horizontal exact min-plus, 4 offsets per iteration ---
    int best = d1;
    {
        int t = 1;
        while (t < W && t * t < best) {
            #pragma unroll
            for (int k = 0; k < 4; ++k) {
                const int tk = t + k;
                const int tt = tk * tk;
                const int jl = j - tk;
                const int jr = j + tk;
                if (jl >= 0) best = min(best, d1row[jl] + tt);
                if (jr < W)  best = min(best, d1row[jr] + tt);
            }
            t += 4;
        }
    }

    float v = p * sqrtf((float)best);

    // --- block reduction: wave shuffle (64 lanes) then LDS ---
    for (int off = 32; off > 0; off >>= 1)
        v += __shfl_down(v, off, 64);
    __shared__ float wsum[8];
    const int lane = j & 63;
    const int wid = j >> 6;
    if (lane == 0) wsum[wid] = v;
    __syncthreads();
    if (j == 0) {
        float s = 0.0f;
        #pragma unroll
        for (int w = 0; w < 8; ++w) s += wsum[w];
        atomicAdd(out, s * INV_N);
    }
}

extern "C" void kernel_launch(void* const* d_in, const int* in_sizes, int n_in,
                              void* d_out, int out_size, void* d_ws, size_t ws_size,
                              hipStream_t stream) {
    const float* probs = (const float*)d_in[0];
    const int* gt = (const int*)d_in[1];
    float* out = (float*)d_out;

    // d_out is re-poisoned (0xAA) before every timed replay: zero it first.
    hipMemsetAsync(out, 0, (size_t)out_size * sizeof(float), stream);

    dim3 grid(BATCH * H);
    dim3 block(W);
    boundary_loss_kernel<<<grid, block, 0, stream>>>(probs, gt, out);
}

// Round 3
// 140.102 us; speedup vs baseline: 1.3636x; 1.3636x over previous
//
#include <hip/hip_runtime.h>
#include <math.h>

// Problem constants (reference: B=16, C=2, H=512, W=512; gt in {0,1})
constexpr int BATCH = 16;
constexpr int H = 512;
constexpr int W = 512;
constexpr int NBLOCKS = BATCH * H;  // 8192
constexpr float INV_N = 1.0f / (float)(16 * 512 * 512);  // mean over B*H*W

// One block per (batch, row): 512 threads, one per column.
// Vertical EDT: batched speculative scan (4 up + 4 down independent loads).
// Horizontal exact min-plus on the d1 row in LDS (exact break t^2 >= best).
// Epilogue: per-block partial sum -> plain store to ws[blockIdx.x].
// (R2 used a single-address atomicAdd from all 8192 blocks; same-address
// fp32 atomics serialize at the L2 RMW unit ~35 cyc each = ~115 us floor,
// which matched R0/R1/R2's invariant timing exactly.)
__global__ __launch_bounds__(512) void boundary_loss_main(
    const float* __restrict__ probs,  // [B, 2, H, W]
    const int* __restrict__ gt,       // [B, 1, H, W]
    float* __restrict__ partial)      // [NBLOCKS]
{
    const int row = blockIdx.x;       // 0 .. B*H-1
    const int b = row >> 9;           // row / 512
    const int i = row & 511;          // row % 512
    const int j = threadIdx.x;        // 0 .. W-1

    const int* colp = gt + (size_t)b * (H * W) + j;

    // Issue the probs load early; consumed only in the epilogue.
    const float p = probs[(size_t)b * 2 * H * W + (size_t)i * W + j];

    // --- vertical nearest-foreground, batched both directions ---
    const int center = colp[i * W];
    int tu = center ? 0 : -1;   // distance to nearest fg at-or-above
    int td = center ? 0 : -1;   // distance to nearest fg at-or-below
    {
        int t = 1;
        const int up_max = i;          // max distance upward
        const int dn_max = H - 1 - i;  // max distance downward
        while (((tu < 0) & (t <= up_max)) | ((td < 0) & (t <= dn_max))) {
            int vu[4], vd[4];
            #pragma unroll
            for (int k = 0; k < 4; ++k) {
                const int ti = t + k;
                vu[k] = (tu < 0 && ti <= up_max) ? colp[(i - ti) * W] : 0;
                vd[k] = (td < 0 && ti <= dn_max) ? colp[(i + ti) * W] : 0;
            }
            #pragma unroll
            for (int k = 0; k < 4; ++k) {
                const int ti = t + k;
                if (tu < 0 && vu[k]) tu = ti;
                if (td < 0 && vd[k]) td = ti;
            }
            t += 4;
        }
    }
    // Reference sentinels (BIG = 2*(H+W) = 2048) for fg-free half-columns:
    const int du = (tu >= 0) ? tu * tu : (i + 2048) * (i + 2048);
    const int dd = (td >= 0) ? td * td : (2560 - i) * (2560 - i);
    const int d1 = min(du, dd);

    __shared__ int d1row[W];
    d1row[j] = d1;
    __syncthreads();

    // --- horizontal exact min-plus, 4 offsets per iteration ---
    int best = d1;
    {
        int t = 1;
        while (t < W && t * t < best) {
            #pragma unroll
            for (int k = 0; k < 4; ++k) {
                const int tk = t + k;
                const int tt = tk * tk;
                const int jl = j - tk;
                const int jr = j + tk;
                if (jl >= 0) best = min(best, d1row[jl] + tt);
                if (jr < W)  best = min(best, d1row[jr] + tt);
            }
            t += 4;
        }
    }

    float v = p * sqrtf((float)best);

    // --- block reduction: wave shuffle (64 lanes) then LDS ---
    for (int off = 32; off > 0; off >>= 1)
        v += __shfl_down(v, off, 64);
    __shared__ float wsum[8];
    const int lane = j & 63;
    const int wid = j >> 6;
    if (lane == 0) wsum[wid] = v;
    __syncthreads();
    if (j == 0) {
        float s = 0.0f;
        #pragma unroll
        for (int w = 0; w < 8; ++w) s += wsum[w];
        partial[row] = s;   // plain store, no contention
    }
}

// Single-block tail: reduce 8192 partials, scale, write the scalar output.
__global__ __launch_bounds__(512) void boundary_loss_reduce(
    const float* __restrict__ partial,  // [NBLOCKS]
    float* __restrict__ out)            // [1]
{
    const int j = threadIdx.x;
    float s = 0.0f;
    #pragma unroll
    for (int k = 0; k < NBLOCKS / 512; ++k)
        s += partial[k * 512 + j];
    for (int off = 32; off > 0; off >>= 1)
        s += __shfl_down(s, off, 64);
    __shared__ float wsum[8];
    const int lane = j & 63;
    const int wid = j >> 6;
    if (lane == 0) wsum[wid] = s;
    __syncthreads();
    if (j == 0) {
        float tot = 0.0f;
        #pragma unroll
        for (int w = 0; w < 8; ++w) tot += wsum[w];
        out[0] = tot * INV_N;   // single writer overwrites poison; no memset needed
    }
}

extern "C" void kernel_launch(void* const* d_in, const int* in_sizes, int n_in,
                              void* d_out, int out_size, void* d_ws, size_t ws_size,
                              hipStream_t stream) {
    const float* probs = (const float*)d_in[0];
    const int* gt = (const int*)d_in[1];
    float* out = (float*)d_out;
    float* partial = (float*)d_ws;  // 8192 floats = 32 KB scratch

    boundary_loss_main<<<dim3(NBLOCKS), dim3(W), 0, stream>>>(probs, gt, partial);
    boundary_loss_reduce<<<dim3(1), dim3(512), 0, stream>>>(partial, out);
}

// Round 4
// 107.038 us; speedup vs baseline: 1.7848x; 1.3089x over previous
//
#include <hip/hip_runtime.h>
#include <math.h>

// Problem constants (reference: B=16, C=2, H=512, W=512; gt in {0,1})
constexpr int BATCH = 16;
constexpr int H = 512;
constexpr int W = 512;
constexpr int NBLOCKS = BATCH * H;  // 8192
constexpr int R = 8;                // register-window radius for vertical scan
constexpr float INV_N = 1.0f / (float)(16 * 512 * 512);  // mean over B*H*W

// One block per (batch, row): 512 threads, one per column.
//
// R3 post-mortem: VGPR_Count=8 showed the compiler serialized the
// "batched" conditional loads (each sunk behind a divergent branch).
// R4: vertical EDT via an UNCONDITIONAL clamped 17-row register window
// (17 independent coalesced loads, one waitcnt, then pure register scan).
// Rare fallback (no fg within +/-8, P~2^-9/direction) continues the scan
// with clamped unconditional 4-batches. Horizontal exact min-plus:
// t=1..4 evaluated unconditionally (8 independent LDS reads), rare tail
// loop for best>25. Partials via plain store (no same-address atomics:
// those serialize at ~34 cyc each = the 115us wall of R0-R2).
__global__ __launch_bounds__(512) void boundary_loss_main(
    const float* __restrict__ probs,  // [B, 2, H, W]
    const int* __restrict__ gt,       // [B, 1, H, W]
    float* __restrict__ partial)      // [NBLOCKS]
{
    const int row = blockIdx.x;       // 0 .. B*H-1
    const int b = row >> 9;           // row / 512
    const int i = row & 511;          // row % 512
    const int j = threadIdx.x;        // 0 .. W-1

    const int* colp = gt + (size_t)b * (H * W) + j;
    const int up_max = i;             // max legal distance upward
    const int dn_max = H - 1 - i;     // max legal distance downward

    // Issue the probs load early; consumed only in the epilogue.
    const float p = probs[(size_t)b * 2 * H * W + (size_t)i * W + j];

    // --- stage a clamped 17-row window into registers (independent loads) ---
    int w[2 * R + 1];
    #pragma unroll
    for (int k = 0; k < 2 * R + 1; ++k) {
        int r = i - R + k;
        r = max(0, min(H - 1, r));
        w[k] = colp[r * W];
    }

    // --- vertical nearest-foreground: pure register scan over the window ---
    int tu = -1, td = -1;
    if (w[R]) { tu = 0; td = 0; }
    #pragma unroll
    for (int t = 1; t <= R; ++t) {
        if (tu < 0 && t <= up_max && w[R - t]) tu = t;
        if (td < 0 && t <= dn_max && w[R + t]) td = t;
    }

    // --- rare fallback: continue outward past +/-R (unconditional clamped) ---
    if (tu < 0 && up_max > R) {
        int t = R + 1;
        while (tu < 0 && t <= up_max) {
            int v[4];
            #pragma unroll
            for (int k = 0; k < 4; ++k) {
                int ti = min(t + k, up_max);
                v[k] = colp[(i - ti) * W];
            }
            #pragma unroll
            for (int k = 0; k < 4; ++k)
                if (tu < 0 && t + k <= up_max && v[k]) tu = t + k;
            t += 4;
        }
    }
    if (td < 0 && dn_max > R) {
        int t = R + 1;
        while (td < 0 && t <= dn_max) {
            int v[4];
            #pragma unroll
            for (int k = 0; k < 4; ++k) {
                int ti = min(t + k, dn_max);
                v[k] = colp[(i + ti) * W];
            }
            #pragma unroll
            for (int k = 0; k < 4; ++k)
                if (td < 0 && t + k <= dn_max && v[k]) td = t + k;
            t += 4;
        }
    }

    // Reference sentinels (BIG = 2*(H+W) = 2048) for fg-free half-columns:
    const int du = (tu >= 0) ? tu * tu : (i + 2048) * (i + 2048);
    const int dd = (td >= 0) ? td * td : (2560 - i) * (2560 - i);
    const int d1 = min(du, dd);

    __shared__ int d1row[W];
    d1row[j] = d1;
    __syncthreads();

    // --- horizontal exact min-plus ---
    // t=1..4 unconditional (8 independent LDS reads, clamped + masked):
    int best = d1;
    #pragma unroll
    for (int t = 1; t <= 4; ++t) {
        const int tt = t * t;
        const int cl = d1row[max(j - t, 0)] + tt;
        const int cr = d1row[min(j + t, W - 1)] + tt;
        if (j - t >= 0) best = min(best, cl);
        if (j + t < W)  best = min(best, cr);
    }
    // Rare tail: only lanes with best > 25 can still improve (t>=5 => +t^2>=25).
    if (best > 25) {
        int t = 5;
        while (t < W && t * t < best) {
            #pragma unroll
            for (int k = 0; k < 2; ++k) {
                const int tk = t + k;
                const int tt = tk * tk;
                const int cl = d1row[max(j - tk, 0)] + tt;
                const int cr = d1row[min(j + tk, W - 1)] + tt;
                if (j - tk >= 0) best = min(best, cl);
                if (j + tk < W)  best = min(best, cr);
            }
            t += 2;
        }
    }

    float v = p * sqrtf((float)best);

    // --- block reduction: wave shuffle (64 lanes) then LDS ---
    for (int off = 32; off > 0; off >>= 1)
        v += __shfl_down(v, off, 64);
    __shared__ float wsum[8];
    const int lane = j & 63;
    const int wid = j >> 6;
    if (lane == 0) wsum[wid] = v;
    __syncthreads();
    if (j == 0) {
        float s = 0.0f;
        #pragma unroll
        for (int wi = 0; wi < 8; ++wi) s += wsum[wi];
        partial[row] = s;   // plain store, no contention
    }
}

// Single-block tail: reduce 8192 partials, scale, write the scalar output.
__global__ __launch_bounds__(512) void boundary_loss_reduce(
    const float* __restrict__ partial,  // [NBLOCKS]
    float* __restrict__ out)            // [1]
{
    const int j = threadIdx.x;
    float s = 0.0f;
    #pragma unroll
    for (int k = 0; k < NBLOCKS / 512; ++k)
        s += partial[k * 512 + j];
    for (int off = 32; off > 0; off >>= 1)
        s += __shfl_down(s, off, 64);
    __shared__ float wsum[8];
    const int lane = j & 63;
    const int wid = j >> 6;
    if (lane == 0) wsum[wid] = s;
    __syncthreads();
    if (j == 0) {
        float tot = 0.0f;
        #pragma unroll
        for (int wi = 0; wi < 8; ++wi) tot += wsum[wi];
        out[0] = tot * INV_N;   // single writer overwrites poison; no memset needed
    }
}

extern "C" void kernel_launch(void* const* d_in, const int* in_sizes, int n_in,
                              void* d_out, int out_size, void* d_ws, size_t ws_size,
                              hipStream_t stream) {
    const float* probs = (const float*)d_in[0];
    const int* gt = (const int*)d_in[1];
    float* out = (float*)d_out;
    float* partial = (float*)d_ws;  // 8192 floats = 32 KB scratch

    boundary_loss_main<<<dim3(NBLOCKS), dim3(W), 0, stream>>>(probs, gt, partial);
    boundary_loss_reduce<<<dim3(1), dim3(512), 0, stream>>>(partial, out);
}

// Round 5
// 99.493 us; speedup vs baseline: 1.9201x; 1.0758x over previous
//
#include <hip/hip_runtime.h>
#include <math.h>

// Problem constants (reference: B=16, C=2, H=512, W=512; gt in {0,1})
constexpr int BATCH = 16;
constexpr int H = 512;
constexpr int W = 512;
constexpr int R = 8;        // register-window radius for vertical scan
constexpr int ROWS = 4;     // output rows per block (window amortization)
constexpr int GRID = BATCH * H / ROWS;  // 2048 blocks
constexpr float INV_N = 1.0f / (float)(16 * 512 * 512);  // mean over B*H*W

// One block per (batch, 4-row group): 512 threads, one per column.
//
// R4 established: unconditional clamped register-window loads beat
// conditional scans (VGPR=8 had serialized everything); same-address
// atomics are a ~115us wall (R0-R2). R5 amortizes: a 20-row register
// window serves the +/-8 vertical scan of 4 consecutive output rows
// (20 loads / 4 rows vs 17 / 1 row), and the block reduction + partial
// store amortize 4x. Grid 8192 -> 2048.
__global__ __launch_bounds__(512) void boundary_loss_main(
    const float* __restrict__ probs,  // [B, 2, H, W]
    const int* __restrict__ gt,       // [B, 1, H, W]
    float* __restrict__ partial)      // [GRID]
{
    const int blk = blockIdx.x;            // 0 .. GRID-1
    const int b = blk >> 7;                // blk / (H/ROWS=128)
    const int i0 = (blk & 127) * ROWS;     // first output row of the group
    const int j = threadIdx.x;             // 0 .. W-1

    const int* colp = gt + (size_t)b * (H * W) + j;

    // probs for the 4 rows: independent coalesced loads, issued early.
    const float* prow = probs + (size_t)b * 2 * H * W + (size_t)i0 * W + j;
    float p[ROWS];
    #pragma unroll
    for (int r = 0; r < ROWS; ++r) p[r] = prow[r * W];

    // --- clamped register window: rows i0-R .. i0+ROWS-1+R (20 loads) ---
    int w[ROWS + 2 * R];
    #pragma unroll
    for (int k = 0; k < ROWS + 2 * R; ++k) {
        int rr = i0 - R + k;
        rr = max(0, min(H - 1, rr));
        w[k] = colp[rr * W];
    }

    // --- vertical nearest-foreground per row: pure register scan ---
    int d1v[ROWS];
    #pragma unroll
    for (int r = 0; r < ROWS; ++r) {
        const int ir = i0 + r;
        const int up_max = ir;
        const int dn_max = H - 1 - ir;
        int tu = -1, td = -1;
        if (w[R + r]) { tu = 0; td = 0; }
        #pragma unroll
        for (int t = 1; t <= R; ++t) {
            if (tu < 0 && t <= up_max && w[R + r - t]) tu = t;
            if (td < 0 && t <= dn_max && w[R + r + t]) td = t;
        }
        // rare fallback: no fg within +/-R in this column (P ~ 2^-9/dir)
        if (tu < 0 && up_max > R) {
            int t = R + 1;
            while (tu < 0 && t <= up_max) {
                int v[4];
                #pragma unroll
                for (int k = 0; k < 4; ++k)
                    v[k] = colp[(ir - min(t + k, up_max)) * W];
                #pragma unroll
                for (int k = 0; k < 4; ++k)
                    if (tu < 0 && t + k <= up_max && v[k]) tu = t + k;
                t += 4;
            }
        }
        if (td < 0 && dn_max > R) {
            int t = R + 1;
            while (td < 0 && t <= dn_max) {
                int v[4];
                #pragma unroll
                for (int k = 0; k < 4; ++k)
                    v[k] = colp[(ir + min(t + k, dn_max)) * W];
                #pragma unroll
                for (int k = 0; k < 4; ++k)
                    if (td < 0 && t + k <= dn_max && v[k]) td = t + k;
                t += 4;
            }
        }
        // Reference sentinels (BIG = 2*(H+W) = 2048) for fg-free half-columns:
        const int du = (tu >= 0) ? tu * tu : (ir + 2048) * (ir + 2048);
        const int dd = (td >= 0) ? td * td : (2560 - ir) * (2560 - ir);
        d1v[r] = min(du, dd);
    }

    __shared__ int d1s[ROWS][W];
    #pragma unroll
    for (int r = 0; r < ROWS; ++r) d1s[r][j] = d1v[r];
    __syncthreads();

    // --- horizontal exact min-plus per row ---
    float v = 0.0f;
    #pragma unroll
    for (int r = 0; r < ROWS; ++r) {
        int best = d1v[r];
        const int* drow = d1s[r];
        #pragma unroll
        for (int t = 1; t <= 4; ++t) {
            const int tt = t * t;
            const int cl = drow[max(j - t, 0)] + tt;
            const int cr = drow[min(j + t, W - 1)] + tt;
            if (j - t >= 0) best = min(best, cl);
            if (j + t < W)  best = min(best, cr);
        }
        // Rare tail: only lanes with best > 25 can still improve.
        if (best > 25) {
            int t = 5;
            while (t < W && t * t < best) {
                #pragma unroll
                for (int k = 0; k < 2; ++k) {
                    const int tk = t + k;
                    const int tt = tk * tk;
                    const int cl = drow[max(j - tk, 0)] + tt;
                    const int cr = drow[min(j + tk, W - 1)] + tt;
                    if (j - tk >= 0) best = min(best, cl);
                    if (j + tk < W)  best = min(best, cr);
                }
                t += 2;
            }
        }
        v += p[r] * sqrtf((float)best);
    }

    // --- block reduction: wave shuffle (64 lanes) then LDS ---
    for (int off = 32; off > 0; off >>= 1)
        v += __shfl_down(v, off, 64);
    __shared__ float wsum[8];
    const int lane = j & 63;
    const int wid = j >> 6;
    if (lane == 0) wsum[wid] = v;
    __syncthreads();
    if (j == 0) {
        float s = 0.0f;
        #pragma unroll
        for (int wi = 0; wi < 8; ++wi) s += wsum[wi];
        partial[blk] = s;   // plain store, no contention
    }
}

// Single-block tail: reduce 2048 partials, scale, write the scalar output.
__global__ __launch_bounds__(512) void boundary_loss_reduce(
    const float* __restrict__ partial,  // [GRID]
    float* __restrict__ out)            // [1]
{
    const int j = threadIdx.x;
    float s = 0.0f;
    #pragma unroll
    for (int k = 0; k < GRID / 512; ++k)
        s += partial[k * 512 + j];
    for (int off = 32; off > 0; off >>= 1)
        s += __shfl_down(s, off, 64);
    __shared__ float wsum[8];
    const int lane = j & 63;
    const int wid = j >> 6;
    if (lane == 0) wsum[wid] = s;
    __syncthreads();
    if (j == 0) {
        float tot = 0.0f;
        #pragma unroll
        for (int wi = 0; wi < 8; ++wi) tot += wsum[wi];
        out[0] = tot * INV_N;   // single writer overwrites poison; no memset needed
    }
}

extern "C" void kernel_launch(void* const* d_in, const int* in_sizes, int n_in,
                              void* d_out, int out_size, void* d_ws, size_t ws_size,
                              hipStream_t stream) {
    const float* probs = (const float*)d_in[0];
    const int* gt = (const int*)d_in[1];
    float* out = (float*)d_out;
    float* partial = (float*)d_ws;  // 2048 floats = 8 KB scratch

    boundary_loss_main<<<dim3(GRID), dim3(W), 0, stream>>>(probs, gt, partial);
    boundary_loss_reduce<<<dim3(1), dim3(512), 0, stream>>>(partial, out);
}

// Round 6
// 94.596 us; speedup vs baseline: 2.0195x; 1.0518x over previous
//
#include <hip/hip_runtime.h>
#include <math.h>

// Problem constants (reference: B=16, C=2, H=512, W=512; gt in {0,1})
constexpr int BATCH = 16;
constexpr int H = 512;
constexpr int W = 512;
constexpr int R = 8;        // window radius for vertical scan
constexpr int ROWS = 8;     // output rows per block
constexpr int GRID = BATCH * H / ROWS;  // 1024 blocks = 4/CU x 256 CU: 1 round
constexpr float INV_N = 1.0f / (float)(16 * 512 * 512);  // mean over B*H*W

// One block per (batch, 8-row group): 512 threads, one per column.
//
// Session facts: same-address atomics = 115us wall (R0-R2); conditional
// loads get serialized by the compiler (R3, VGPR=8); unconditional clamped
// window loads fix it (R4); row-group amortization helps (R5).
// R6: (a) gt is 0/1 -> pack the 24-row window into a 24-bit mask
//     (one v_lshl_or per row), vertical nearest-fg = clz/ctz: ~10 ops/row
//     vs ~70 for the cndmask scan. Clamped duplicate bits are farther than
//     the true edge-row bit, and highest/lowest-bit selection takes the
//     nearest, so no validity masking needed (exact).
// (b) ROWS=8 -> 1024 blocks = exactly 4 blocks/CU: single dispatch round.
__global__ __launch_bounds__(512) void boundary_loss_main(
    const float* __restrict__ probs,  // [B, 2, H, W]
    const int* __restrict__ gt,       // [B, 1, H, W]
    float* __restrict__ partial)      // [GRID]
{
    const int blk = blockIdx.x;            // 0 .. GRID-1
    const int b = blk >> 6;                // blk / (H/ROWS=64)
    const int i0 = (blk & 63) * ROWS;      // first output row of the group
    const int j = threadIdx.x;             // 0 .. W-1

    const int* colp = gt + (size_t)b * (H * W) + j;

    // probs for the 8 rows: independent coalesced loads, issued early.
    const float* prow = probs + (size_t)b * 2 * H * W + (size_t)i0 * W + j;
    float p[ROWS];
    #pragma unroll
    for (int r = 0; r < ROWS; ++r) p[r] = prow[r * W];

    // --- pack the clamped 24-row window into a bit mask ---
    unsigned mask = 0;
    #pragma unroll
    for (int k = 0; k < ROWS + 2 * R; ++k) {
        int rr = i0 - R + k;
        rr = max(0, min(H - 1, rr));
        mask |= ((unsigned)colp[rr * W] & 1u) << k;
    }

    // --- vertical nearest-foreground per row via clz/ctz ---
    int d1v[ROWS];
    #pragma unroll
    for (int r = 0; r < ROWS; ++r) {
        const int ir = i0 + r;
        const int c = R + r;               // this row's bit position
        const int up_max = ir;
        const int dn_max = H - 1 - ir;
        const unsigned m_up = mask & ((2u << c) - 1);  // bits 0..c
        const unsigned m_dn = mask >> c;               // bits c..23
        int tu = m_up ? (c - (31 - __clz((int)m_up))) : -1;
        int td = m_dn ? (__ffs((int)m_dn) - 1) : -1;
        // rare fallback: no fg within +/-R in this column (P ~ 2^-9/dir)
        if (tu < 0 && up_max > R) {
            int t = R + 1;
            while (tu < 0 && t <= up_max) {
                int v[4];
                #pragma unroll
                for (int k = 0; k < 4; ++k)
                    v[k] = colp[(ir - min(t + k, up_max)) * W];
                #pragma unroll
                for (int k = 0; k < 4; ++k)
                    if (tu < 0 && t + k <= up_max && v[k]) tu = t + k;
                t += 4;
            }
        }
        if (td < 0 && dn_max > R) {
            int t = R + 1;
            while (td < 0 && t <= dn_max) {
                int v[4];
                #pragma unroll
                for (int k = 0; k < 4; ++k)
                    v[k] = colp[(ir + min(t + k, dn_max)) * W];
                #pragma unroll
                for (int k = 0; k < 4; ++k)
                    if (td < 0 && t + k <= dn_max && v[k]) td = t + k;
                t += 4;
            }
        }
        // Reference sentinels (BIG = 2*(H+W) = 2048) for fg-free half-columns:
        const int du = (tu >= 0) ? tu * tu : (ir + 2048) * (ir + 2048);
        const int dd = (td >= 0) ? td * td : (2560 - ir) * (2560 - ir);
        d1v[r] = min(du, dd);
    }

    __shared__ int d1s[ROWS][W];
    #pragma unroll
    for (int r = 0; r < ROWS; ++r) d1s[r][j] = d1v[r];
    __syncthreads();

    // --- horizontal exact min-plus per row ---
    float v = 0.0f;
    #pragma unroll
    for (int r = 0; r < ROWS; ++r) {
        int best = d1v[r];
        const int* drow = d1s[r];
        #pragma unroll
        for (int t = 1; t <= 4; ++t) {
            const int tt = t * t;
            const int cl = drow[max(j - t, 0)] + tt;
            const int cr = drow[min(j + t, W - 1)] + tt;
            if (j - t >= 0) best = min(best, cl);
            if (j + t < W)  best = min(best, cr);
        }
        // Rare tail: only lanes with best > 25 can still improve.
        if (best > 25) {
            int t = 5;
            while (t < W && t * t < best) {
                #pragma unroll
                for (int k = 0; k < 2; ++k) {
                    const int tk = t + k;
                    const int tt = tk * tk;
                    const int cl = drow[max(j - tk, 0)] + tt;
                    const int cr = drow[min(j + tk, W - 1)] + tt;
                    if (j - tk >= 0) best = min(best, cl);
                    if (j + tk < W)  best = min(best, cr);
                }
                t += 2;
            }
        }
        v += p[r] * sqrtf((float)best);
    }

    // --- block reduction: wave shuffle (64 lanes) then LDS ---
    for (int off = 32; off > 0; off >>= 1)
        v += __shfl_down(v, off, 64);
    __shared__ float wsum[8];
    const int lane = j & 63;
    const int wid = j >> 6;
    if (lane == 0) wsum[wid] = v;
    __syncthreads();
    if (j == 0) {
        float s = 0.0f;
        #pragma unroll
        for (int wi = 0; wi < 8; ++wi) s += wsum[wi];
        partial[blk] = s;   // plain store, no contention
    }
}

// Single-block tail: reduce 1024 partials, scale, write the scalar output.
__global__ __launch_bounds__(512) void boundary_loss_reduce(
    const float* __restrict__ partial,  // [GRID]
    float* __restrict__ out)            // [1]
{
    const int j = threadIdx.x;
    float s = 0.0f;
    #pragma unroll
    for (int k = 0; k < GRID / 512; ++k)
        s += partial[k * 512 + j];
    for (int off = 32; off > 0; off >>= 1)
        s += __shfl_down(s, off, 64);
    __shared__ float wsum[8];
    const int lane = j & 63;
    const int wid = j >> 6;
    if (lane == 0) wsum[wid] = s;
    __syncthreads();
    if (j == 0) {
        float tot = 0.0f;
        #pragma unroll
        for (int wi = 0; wi < 8; ++wi) tot += wsum[wi];
        out[0] = tot * INV_N;   // single writer overwrites poison; no memset needed
    }
}

extern "C" void kernel_launch(void* const* d_in, const int* in_sizes, int n_in,
                              void* d_out, int out_size, void* d_ws, size_t ws_size,
                              hipStream_t stream) {
    const float* probs = (const float*)d_in[0];
    const int* gt = (const int*)d_in[1];
    float* out = (float*)d_out;
    float* partial = (float*)d_ws;  // 1024 floats = 4 KB scratch

    boundary_loss_main<<<dim3(GRID), dim3(W), 0, stream>>>(probs, gt, partial);
    boundary_loss_reduce<<<dim3(1), dim3(512), 0, stream>>>(partial, out);
}

// Round 7
// 93.128 us; speedup vs baseline: 2.0514x; 1.0158x over previous
//
#include <hip/hip_runtime.h>
#include <math.h>

// Problem constants (reference: B=16, C=2, H=512, W=512; gt in {0,1})
constexpr int BATCH = 16;
constexpr int H = 512;
constexpr int W = 512;
constexpr int R = 8;        // window radius for vertical scan
constexpr int ROWS = 16;    // output rows per block (window = 32 = one uint)
constexpr int GRID = BATCH * H / ROWS;  // 512 blocks = 2/CU x 256 CU: 1 round
constexpr float INV_N = 1.0f / (float)(16 * 512 * 512);  // mean over B*H*W

// One block per (batch, 16-row group): 512 threads, one per column.
//
// Session facts: same-address atomics = 115us wall (R0-R2); conditional
// loads get serialized by the compiler (R3, VGPR=8); unconditional clamped
// window loads fix it (R4); row-group amortization works (R5, R6).
// R7: ROWS=16 -> the 32-row clamped window packs into exactly one 32-bit
// mask; gt redundancy drops 3x -> 2x (FETCH ~73 -> ~50 MB, kernel is
// near-BW-bound); GRID=512 = 2 blocks/CU, still one dispatch round.
// Vertical nearest-fg per row = clz/ffs on the mask (~10 VALU ops/row).
// Clamped duplicate bits are always >= as far as the real bit they copy,
// and clz/ffs pick the nearest set bit, so clamping needs no masking.
__global__ __launch_bounds__(512) void boundary_loss_main(
    const float* __restrict__ probs,  // [B, 2, H, W]
    const int* __restrict__ gt,       // [B, 1, H, W]
    float* __restrict__ partial)      // [GRID]
{
    const int blk = blockIdx.x;            // 0 .. GRID-1
    const int b = blk >> 5;                // blk / (H/ROWS=32)
    const int i0 = (blk & 31) * ROWS;      // first output row of the group
    const int j = threadIdx.x;             // 0 .. W-1

    const int* colp = gt + (size_t)b * (H * W) + j;

    // probs for the 16 rows: independent coalesced loads, issued early.
    const float* prow = probs + (size_t)b * 2 * H * W + (size_t)i0 * W + j;
    float p[ROWS];
    #pragma unroll
    for (int r = 0; r < ROWS; ++r) p[r] = prow[r * W];

    // --- pack the clamped 32-row window into one 32-bit mask ---
    unsigned mask = 0;
    #pragma unroll
    for (int k = 0; k < ROWS + 2 * R; ++k) {
        int rr = i0 - R + k;
        rr = max(0, min(H - 1, rr));
        mask |= ((unsigned)colp[rr * W] & 1u) << k;
    }

    // --- vertical nearest-foreground per row via clz/ffs ---
    int d1v[ROWS];
    #pragma unroll
    for (int r = 0; r < ROWS; ++r) {
        const int ir = i0 + r;
        const int c = R + r;               // this row's bit position (8..23)
        const int up_max = ir;
        const int dn_max = H - 1 - ir;
        const unsigned m_up = (c == 31) ? mask : (mask & ((2u << c) - 1));
        const unsigned m_dn = mask >> c;
        int tu = m_up ? (c - (31 - __clz((int)m_up))) : -1;
        int td = m_dn ? (__ffs((int)m_dn) - 1) : -1;
        // rare fallback: no fg within the window reach (P ~ 2^-9/dir)
        if (tu < 0 && up_max > c) {
            int t = c + 1;
            while (tu < 0 && t <= up_max) {
                int v[4];
                #pragma unroll
                for (int k = 0; k < 4; ++k)
                    v[k] = colp[(ir - min(t + k, up_max)) * W];
                #pragma unroll
                for (int k = 0; k < 4; ++k)
                    if (tu < 0 && t + k <= up_max && v[k]) tu = t + k;
                t += 4;
            }
        }
        const int dn_reach = 31 - c;
        if (td < 0 && dn_max > dn_reach) {
            int t = dn_reach + 1;
            while (td < 0 && t <= dn_max) {
                int v[4];
                #pragma unroll
                for (int k = 0; k < 4; ++k)
                    v[k] = colp[(ir + min(t + k, dn_max)) * W];
                #pragma unroll
                for (int k = 0; k < 4; ++k)
                    if (td < 0 && t + k <= dn_max && v[k]) td = t + k;
                t += 4;
            }
        }
        // Reference sentinels (BIG = 2*(H+W) = 2048) for fg-free half-columns:
        const int du = (tu >= 0) ? tu * tu : (ir + 2048) * (ir + 2048);
        const int dd = (td >= 0) ? td * td : (2560 - ir) * (2560 - ir);
        d1v[r] = min(du, dd);
    }

    __shared__ int d1s[ROWS][W];
    #pragma unroll
    for (int r = 0; r < ROWS; ++r) d1s[r][j] = d1v[r];
    __syncthreads();

    // --- horizontal exact min-plus per row ---
    float v = 0.0f;
    #pragma unroll
    for (int r = 0; r < ROWS; ++r) {
        int best = d1v[r];
        const int* drow = d1s[r];
        #pragma unroll
        for (int t = 1; t <= 4; ++t) {
            const int tt = t * t;
            const int cl = drow[max(j - t, 0)] + tt;
            const int cr = drow[min(j + t, W - 1)] + tt;
            if (j - t >= 0) best = min(best, cl);
            if (j + t < W)  best = min(best, cr);
        }
        // Rare tail: only lanes with best > 25 can still improve.
        if (best > 25) {
            int t = 5;
            while (t < W && t * t < best) {
                #pragma unroll
                for (int k = 0; k < 2; ++k) {
                    const int tk = t + k;
                    const int tt = tk * tk;
                    const int cl = drow[max(j - tk, 0)] + tt;
                    const int cr = drow[min(j + tk, W - 1)] + tt;
                    if (j - tk >= 0) best = min(best, cl);
                    if (j + tk < W)  best = min(best, cr);
                }
                t += 2;
            }
        }
        v += p[r] * sqrtf((float)best);
    }

    // --- block reduction: wave shuffle (64 lanes) then LDS ---
    for (int off = 32; off > 0; off >>= 1)
        v += __shfl_down(v, off, 64);
    __shared__ float wsum[8];
    const int lane = j & 63;
    const int wid = j >> 6;
    if (lane == 0) wsum[wid] = v;
    __syncthreads();
    if (j == 0) {
        float s = 0.0f;
        #pragma unroll
        for (int wi = 0; wi < 8; ++wi) s += wsum[wi];
        partial[blk] = s;   // plain store, no contention
    }
}

// Single-block tail: reduce 512 partials, scale, write the scalar output.
__global__ __launch_bounds__(512) void boundary_loss_reduce(
    const float* __restrict__ partial,  // [GRID]
    float* __restrict__ out)            // [1]
{
    const int j = threadIdx.x;
    float s = (j < GRID) ? partial[j] : 0.0f;
    for (int off = 32; off > 0; off >>= 1)
        s += __shfl_down(s, off, 64);
    __shared__ float wsum[8];
    const int lane = j & 63;
    const int wid = j >> 6;
    if (lane == 0) wsum[wid] = s;
    __syncthreads();
    if (j == 0) {
        float tot = 0.0f;
        #pragma unroll
        for (int wi = 0; wi < 8; ++wi) tot += wsum[wi];
        out[0] = tot * INV_N;   // single writer overwrites poison; no memset needed
    }
}

extern "C" void kernel_launch(void* const* d_in, const int* in_sizes, int n_in,
                              void* d_out, int out_size, void* d_ws, size_t ws_size,
                              hipStream_t stream) {
    const float* probs = (const float*)d_in[0];
    const int* gt = (const int*)d_in[1];
    float* out = (float*)d_out;
    float* partial = (float*)d_ws;  // 512 floats = 2 KB scratch

    boundary_loss_main<<<dim3(GRID), dim3(W), 0, stream>>>(probs, gt, partial);
    boundary_loss_reduce<<<dim3(1), dim3(512), 0, stream>>>(partial, out);
}

// Round 8
// 88.815 us; speedup vs baseline: 2.1510x; 1.0486x over previous
//
#include <hip/hip_runtime.h>
#include <math.h>

// Problem constants (reference: B=16, C=2, H=512, W=512; gt in {0,1})
constexpr int BATCH = 16;
constexpr int H = 512;
constexpr int W = 512;
constexpr int R = 8;        // window radius for vertical scan
constexpr int ROWS = 16;    // output rows per block (window = 32 = one uint)
constexpr int GRID = BATCH * H / ROWS;  // 512 blocks = 2/CU x 256 CU: 1 round
constexpr int PADW = W + 8; // d1 row padded by 4 sentinels each side
constexpr int BIG = 8000000;  // > max legal best (511+2048)^2 ~ 6.55e6
constexpr float INV_N = 1.0f / (float)(16 * 512 * 512);  // mean over B*H*W

// One block per (batch, 16-row group): 512 threads.
//
// Session facts: same-address atomics = 115us wall (R0-R2); conditional
// loads get serialized (R3); unconditional clamped window loads fix it
// (R4); row-group amortization works (R5-R7); 32-bit mask + clz/ffs
// vertical scan (R7).
// R8: horizontal pass was LDS-pipe-bound (128 ds_read_b32/thread ~5us/CU
// aggregate). Re-map phase 2: thread handles 4 consecutive columns of one
// row -> 3 aligned ds_read_b128 on a +/-4-padded d1 row replace 16
// ds_read_b32; probs loads become float4. Sentinel pad BIG never wins
// (best <= own d1 <= 6.55e6 < BIG) and never overflows (+16). XCD swizzle:
// 8 consecutive row-groups (sharing half their gt windows) per XCD for L2
// reuse of the window overlap.
__global__ __launch_bounds__(512) void boundary_loss_main(
    const float* __restrict__ probs,  // [B, 2, H, W]
    const int* __restrict__ gt,       // [B, 1, H, W]
    float* __restrict__ partial)      // [GRID]
{
    // XCD swizzle: logical = (hw & 63)*8 + (hw >> 6); consecutive logical
    // groups then share an XCD (dispatch is round-robin hw % 8).
    const int hw = blockIdx.x;
    const int blk = ((hw & 63) << 3) | (hw >> 6);
    const int b = blk >> 5;                // 32 groups per batch
    const int i0 = (blk & 31) * ROWS;      // first output row of the group
    const int j = threadIdx.x;             // 0 .. 511

    const int* colp = gt + (size_t)b * (H * W) + j;

    // --- phase 1: pack the clamped 32-row window into one 32-bit mask ---
    int wv[ROWS + 2 * R];
    #pragma unroll
    for (int k = 0; k < ROWS + 2 * R; ++k) {
        int rr = i0 - R + k;
        rr = max(0, min(H - 1, rr));
        wv[k] = colp[rr * W];
    }
    unsigned mask = 0;
    #pragma unroll
    for (int k = 0; k < ROWS + 2 * R; ++k)
        mask |= ((unsigned)wv[k] & 1u) << k;

    __shared__ __align__(16) int d1s[ROWS][PADW];
    // sentinel pads: 16 rows x 8 slots, threads 0..127 write one each
    if (j < 128) {
        const int rr = j >> 3, slot = j & 7;
        const int idx = (slot < 4) ? slot : (W + slot);
        d1s[rr][idx] = BIG;
    }

    // --- vertical nearest-foreground per row via clz/ffs ---
    #pragma unroll
    for (int r = 0; r < ROWS; ++r) {
        const int ir = i0 + r;
        const int c = R + r;               // bit position (8..23)
        const int up_max = ir;
        const int dn_max = H - 1 - ir;
        const unsigned m_up = mask & ((2u << c) - 1);
        const unsigned m_dn = mask >> c;
        int tu = m_up ? (c - (31 - __clz((int)m_up))) : -1;
        int td = m_dn ? (__ffs((int)m_dn) - 1) : -1;
        // rare fallback: no fg within window reach (P ~ 2^-9/dir)
        if (tu < 0 && up_max > c) {
            int t = c + 1;
            while (tu < 0 && t <= up_max) {
                int v[4];
                #pragma unroll
                for (int k = 0; k < 4; ++k)
                    v[k] = colp[(ir - min(t + k, up_max)) * W];
                #pragma unroll
                for (int k = 0; k < 4; ++k)
                    if (tu < 0 && t + k <= up_max && v[k]) tu = t + k;
                t += 4;
            }
        }
        const int dn_reach = 31 - c;
        if (td < 0 && dn_max > dn_reach) {
            int t = dn_reach + 1;
            while (td < 0 && t <= dn_max) {
                int v[4];
                #pragma unroll
                for (int k = 0; k < 4; ++k)
                    v[k] = colp[(ir + min(t + k, dn_max)) * W];
                #pragma unroll
                for (int k = 0; k < 4; ++k)
                    if (td < 0 && t + k <= dn_max && v[k]) td = t + k;
                t += 4;
            }
        }
        // Reference sentinels (BIG=2*(H+W)=2048) for fg-free half-columns:
        const int du = (tu >= 0) ? tu * tu : (ir + 2048) * (ir + 2048);
        const int dd = (td >= 0) ? td * td : (2560 - ir) * (2560 - ir);
        d1s[r][4 + j] = min(du, dd);
    }
    __syncthreads();

    // --- phase 2: horizontal exact min-plus, 4 columns/thread/task ---
    // tasks: 16 rows x 128 col-quads = 2048; 4 passes of 512 threads.
    const float* pbase = probs + (size_t)b * 2 * H * W + (size_t)i0 * W;
    float v = 0.0f;
    #pragma unroll
    for (int pass = 0; pass < 4; ++pass) {
        const int tau = pass * 512 + j;
        const int row = tau >> 7;          // 0..15
        const int jc = (tau & 127) << 2;   // 0..508, multiple of 4
        const int* drow = d1s[row];
        const int4* qp = (const int4*)(drow + jc);  // 16B aligned
        const int4 qa = qp[0], qb = qp[1], qc = qp[2];
        const int win[12] = {qa.x, qa.y, qa.z, qa.w,
                             qb.x, qb.y, qb.z, qb.w,
                             qc.x, qc.y, qc.z, qc.w};
        const float4 p4 = *(const float4*)(pbase + (size_t)row * W + jc);
        const float pv[4] = {p4.x, p4.y, p4.z, p4.w};
        #pragma unroll
        for (int m = 0; m < 4; ++m) {
            int best = win[4 + m];
            #pragma unroll
            for (int t = 1; t <= 4; ++t) {
                best = min(best, win[4 + m - t] + t * t);
                best = min(best, win[4 + m + t] + t * t);
            }
            // Rare tail: only if best > 25 can t>=5 still improve.
            if (best > 25) {
                const int c0 = jc + m;
                int t = 5;
                while (t < W && t * t < best) {
                    if (c0 - t >= 0) best = min(best, drow[4 + c0 - t] + t * t);
                    if (c0 + t <  W) best = min(best, drow[4 + c0 + t] + t * t);
                    ++t;
                }
            }
            v += pv[m] * sqrtf((float)best);
        }
    }

    // --- block reduction: wave shuffle (64 lanes) then LDS ---
    for (int off = 32; off > 0; off >>= 1)
        v += __shfl_down(v, off, 64);
    __shared__ float wsum[8];
    const int lane = j & 63;
    const int wid = j >> 6;
    if (lane == 0) wsum[wid] = v;
    __syncthreads();
    if (j == 0) {
        float s = 0.0f;
        #pragma unroll
        for (int wi = 0; wi < 8; ++wi) s += wsum[wi];
        partial[blk] = s;   // plain store, no contention
    }
}

// Single-block tail: reduce 512 partials, scale, write the scalar output.
__global__ __launch_bounds__(512) void boundary_loss_reduce(
    const float* __restrict__ partial,  // [GRID]
    float* __restrict__ out)            // [1]
{
    const int j = threadIdx.x;
    float s = (j < GRID) ? partial[j] : 0.0f;
    for (int off = 32; off > 0; off >>= 1)
        s += __shfl_down(s, off, 64);
    __shared__ float wsum[8];
    const int lane = j & 63;
    const int wid = j >> 6;
    if (lane == 0) wsum[wid] = s;
    __syncthreads();
    if (j == 0) {
        float tot = 0.0f;
        #pragma unroll
        for (int wi = 0; wi < 8; ++wi) tot += wsum[wi];
        out[0] = tot * INV_N;   // single writer overwrites poison; no memset needed
    }
}

extern "C" void kernel_launch(void* const* d_in, const int* in_sizes, int n_in,
                              void* d_out, int out_size, void* d_ws, size_t ws_size,
                              hipStream_t stream) {
    const float* probs = (const float*)d_in[0];
    const int* gt = (const int*)d_in[1];
    float* out = (float*)d_out;
    float* partial = (float*)d_ws;  // 512 floats = 2 KB scratch

    boundary_loss_main<<<dim3(GRID), dim3(512), 0, stream>>>(probs, gt, partial);
    boundary_loss_reduce<<<dim3(1), dim3(512), 0, stream>>>(partial, out);
}